// Round 4
// baseline (73.580 us; speedup 1.0000x reference)
//
#include <hip/hip_runtime.h>

#define B_ROWS   32768
#define NUM_CLS  1000
#define FEAT     512

#define BLOCKS          1024
#define WAVES_PER_BLOCK 4
#define ROWS_PER_WAVE   8      // 1024 blocks * 4 waves * 8 rows = 32768

typedef float f32x4 __attribute__((ext_vector_type(4)));

// ws layout (floats):
//   [1]              count of class C-2
//   [2]              count of class C-1
//   [3]              done-block counter (uint32)
//   [64 .. 576)      feature sums for class C-2
//   [576 .. 1088)    feature sums for class C-1
//   [1088 .. 2112)   per-block intra partials (written unconditionally, no zero needed)
#define WS_CNT0   1
#define WS_CNT1   2
#define WS_DONE   3
#define WS_SUM0   64
#define WS_SUM1   (64 + 512)
#define WS_PART   (64 + 1024)
#define WS_ZERO_FLOATS (64 + 1024)

__global__ __launch_bounds__(256) void loss_fused(
    const float* __restrict__ features,
    const int*   __restrict__ labels,
    const float* __restrict__ center,
    float*       __restrict__ ws,
    float*       __restrict__ out)
{
    const int wave = threadIdx.x >> 6;
    const int lane = threadIdx.x & 63;
    const int wid  = blockIdx.x * WAVES_PER_BLOCK + wave;
    const int base_row = wid * ROWS_PER_WAVE;

    // lanes 0..7 hold this wave's 8 labels (replicated in upper lanes)
    const int mylab = labels[base_row + (lane & 7)];

    float p[ROWS_PER_WAVE];   // per-lane partial sum-of-squares, one per row

    #pragma unroll
    for (int r = 0; r < ROWS_PER_WAVE; ++r) {
        const int row = base_row + r;
        const int lab = __shfl(mylab, r);

        const f32x4* frow = (const f32x4*)(features + (size_t)row * FEAT);
        const f32x4* crow = (const f32x4*)(center   + (size_t)lab * FEAT);

        f32x4 f0 = __builtin_nontemporal_load(&frow[lane]);       // streamed once
        f32x4 f1 = __builtin_nontemporal_load(&frow[lane + 64]);
        f32x4 c0 = crow[lane];                                    // cache-friendly
        f32x4 c1 = crow[lane + 64];

        f32x4 d0 = f0 - c0;
        f32x4 d1 = f1 - c1;

        p[r] = d0.x*d0.x + d0.y*d0.y + d0.z*d0.z + d0.w*d0.w
             + d1.x*d1.x + d1.y*d1.y + d1.z*d1.z + d1.w*d1.w;

        // Inter-loss bookkeeping: classes C-2/C-1 only (~65 of 32768 rows)
        if (lab >= NUM_CLS - 2) {
            float* sums = ws + (lab == NUM_CLS - 2 ? WS_SUM0 : WS_SUM1);
            const int base = lane * 4;
            atomicAdd(&sums[base + 0],   f0.x);
            atomicAdd(&sums[base + 1],   f0.y);
            atomicAdd(&sums[base + 2],   f0.z);
            atomicAdd(&sums[base + 3],   f0.w);
            atomicAdd(&sums[base + 256], f1.x);
            atomicAdd(&sums[base + 257], f1.y);
            atomicAdd(&sums[base + 258], f1.z);
            atomicAdd(&sums[base + 259], f1.w);
            if (lane == 0)
                atomicAdd(&ws[lab == NUM_CLS - 2 ? WS_CNT0 : WS_CNT1], 1.0f);
        }
    }

    // ---- multi-value reduction: 8 row-sums across 64 lanes in 13 shuffles ----
    const bool b0 = lane & 1, b1 = lane & 2, b2 = lane & 4;

    float q[4];
    #pragma unroll
    for (int i = 0; i < 4; ++i) {
        float send = b0 ? p[i]     : p[4 + i];
        float keep = b0 ? p[4 + i] : p[i];
        q[i] = keep + __shfl_xor(send, 1);
    }
    float w2[2];
    #pragma unroll
    for (int i = 0; i < 2; ++i) {
        float send = b1 ? q[i]     : q[2 + i];
        float keep = b1 ? q[2 + i] : q[i];
        w2[i] = keep + __shfl_xor(send, 2);
    }
    {
        float send = b2 ? w2[0] : w2[1];
        float keep = b2 ? w2[1] : w2[0];
        float u = keep + __shfl_xor(send, 4);
        u += __shfl_xor(u, 8);
        u += __shfl_xor(u, 16);
        u += __shfl_xor(u, 32);
        // lane holds the full 64-lane sum for row (4*b0 + 2*b1 + b2)
        float dist = sqrtf(u);
        dist = fminf(fmaxf(dist, 1e-12f), 1e12f);
        // sum the 8 distinct rows within each 8-lane group
        dist += __shfl_xor(dist, 1);
        dist += __shfl_xor(dist, 2);
        dist += __shfl_xor(dist, 4);
        p[0] = dist;   // every lane: sum of this wave's 8 row-distances
    }

    __shared__ float s[WAVES_PER_BLOCK];
    __shared__ int isLast;
    if (lane == 0) s[wave] = p[0];
    __syncthreads();

    if (threadIdx.x == 0) {
        ws[WS_PART + blockIdx.x] = s[0] + s[1] + s[2] + s[3];
        __threadfence();                                   // release partials + atomics
        unsigned old = atomicAdd((unsigned*)&ws[WS_DONE], 1u);
        isLast = (old == BLOCKS - 1);
    }
    __syncthreads();
    if (!isLast) return;

    // ---- final reduction: only the last-done block runs this ----
    __threadfence();                                       // acquire
    const int t = threadIdx.x;

#define WSLD(i) __hip_atomic_load(&ws[(i)], __ATOMIC_RELAXED, __HIP_MEMORY_SCOPE_AGENT)

    const float cnt0 = fmaxf(WSLD(WS_CNT0), 1.0f);
    const float cnt1 = fmaxf(WSLD(WS_CNT1), 1.0f);

    float p_inter = 0.0f;
    #pragma unroll
    for (int k = 0; k < 2; ++k) {
        const int d = t * 2 + k;
        float a = (center[(size_t)(NUM_CLS - 2) * FEAT + d] + WSLD(WS_SUM0 + d)) / cnt0;
        float b = (center[(size_t)(NUM_CLS - 1) * FEAT + d] + WSLD(WS_SUM1 + d)) / cnt1;
        float df = a - b;
        p_inter += df * df;
    }

    float p_intra = WSLD(WS_PART + t)       + WSLD(WS_PART + t + 256)
                  + WSLD(WS_PART + t + 512) + WSLD(WS_PART + t + 768);

    #pragma unroll
    for (int off = 32; off; off >>= 1) {
        p_inter += __shfl_xor(p_inter, off);
        p_intra += __shfl_xor(p_intra, off);
    }

    __shared__ float si[4], sa[4];
    if ((t & 63) == 0) { si[t >> 6] = p_inter; sa[t >> 6] = p_intra; }
    __syncthreads();

    if (t == 0) {
        float d_last = sqrtf(si[0] + si[1] + si[2] + si[3]);
        out[0] = (sa[0] + sa[1] + sa[2] + sa[3]) * (1.0f / (float)B_ROWS);
        out[1] = (2.0f / d_last) * (1.0f / ((float)NUM_CLS * (float)(NUM_CLS - 1)));
    }
}

extern "C" void kernel_launch(void* const* d_in, const int* in_sizes, int n_in,
                              void* d_out, int out_size, void* d_ws, size_t ws_size,
                              hipStream_t stream) {
    const float* features = (const float*)d_in[0];
    const int*   labels   = (const int*)d_in[1];
    const float* center   = (const float*)d_in[2];
    float* out = (float*)d_out;
    float* ws  = (float*)d_ws;

    (void)hipMemsetAsync(ws, 0, WS_ZERO_FLOATS * sizeof(float), stream);

    loss_fused<<<BLOCKS, 256, 0, stream>>>(features, labels, center, ws, out);
}

// Round 5
// 59.922 us; speedup vs baseline: 1.2279x; 1.2279x over previous
//
#include <hip/hip_runtime.h>

#define B_ROWS   32768
#define NUM_CLS  1000
#define FEAT     512

#define BLOCKS          1024
#define THREADS         512
#define WAVES_PER_BLOCK 8
#define ROWS_PER_WAVE   4      // 1024 blocks * 8 waves * 4 rows = 32768

typedef float f32x4 __attribute__((ext_vector_type(4)));

// ws layout (floats):
//   [1]              count of class C-2
//   [2]              count of class C-1
//   [3]              done-block counter (uint32)
//   [64 .. 576)      feature sums for class C-2
//   [576 .. 1088)    feature sums for class C-1
//   [1088 .. 2112)   per-block intra partials (written unconditionally, no zero needed)
#define WS_CNT0   1
#define WS_CNT1   2
#define WS_DONE   3
#define WS_SUM0   64
#define WS_SUM1   (64 + 512)
#define WS_PART   (64 + 1024)
#define WS_ZERO_FLOATS (64 + 1024)

__global__ __launch_bounds__(THREADS) void loss_fused(
    const float* __restrict__ features,
    const int*   __restrict__ labels,
    const float* __restrict__ center,
    float*       __restrict__ ws,
    float*       __restrict__ out)
{
    const int wave = threadIdx.x >> 6;
    const int lane = threadIdx.x & 63;
    const int wid  = blockIdx.x * WAVES_PER_BLOCK + wave;
    const int base_row = wid * ROWS_PER_WAVE;

    // lanes 0..3 hold this wave's 4 labels (replicated in upper lanes)
    const int mylab = labels[base_row + (lane & 3)];

    float p[ROWS_PER_WAVE];   // per-lane partial sum-of-squares, one per row

    #pragma unroll
    for (int r = 0; r < ROWS_PER_WAVE; ++r) {
        const int row = base_row + r;
        const int lab = __shfl(mylab, r);

        const f32x4* frow = (const f32x4*)(features + (size_t)row * FEAT);
        const f32x4* crow = (const f32x4*)(center   + (size_t)lab * FEAT);

        f32x4 f0 = frow[lane];          // plain cached loads: L3-resident across replays
        f32x4 f1 = frow[lane + 64];
        f32x4 c0 = crow[lane];
        f32x4 c1 = crow[lane + 64];

        f32x4 d0 = f0 - c0;
        f32x4 d1 = f1 - c1;

        p[r] = d0.x*d0.x + d0.y*d0.y + d0.z*d0.z + d0.w*d0.w
             + d1.x*d1.x + d1.y*d1.y + d1.z*d1.z + d1.w*d1.w;

        // Inter-loss bookkeeping: classes C-2/C-1 only (~65 of 32768 rows)
        if (lab >= NUM_CLS - 2) {
            float* sums = ws + (lab == NUM_CLS - 2 ? WS_SUM0 : WS_SUM1);
            const int base = lane * 4;
            atomicAdd(&sums[base + 0],   f0.x);
            atomicAdd(&sums[base + 1],   f0.y);
            atomicAdd(&sums[base + 2],   f0.z);
            atomicAdd(&sums[base + 3],   f0.w);
            atomicAdd(&sums[base + 256], f1.x);
            atomicAdd(&sums[base + 257], f1.y);
            atomicAdd(&sums[base + 258], f1.z);
            atomicAdd(&sums[base + 259], f1.w);
            if (lane == 0)
                atomicAdd(&ws[lab == NUM_CLS - 2 ? WS_CNT0 : WS_CNT1], 1.0f);
        }
    }

    // ---- multi-value reduction: 4 row-sums across 64 lanes in 9 shuffles ----
    const bool b0 = lane & 1, b1 = lane & 2;

    float q[2];
    #pragma unroll
    for (int i = 0; i < 2; ++i) {
        float send = b0 ? p[i]     : p[2 + i];
        float keep = b0 ? p[2 + i] : p[i];
        q[i] = keep + __shfl_xor(send, 1);
    }
    {
        float send = b1 ? q[0] : q[1];
        float keep = b1 ? q[1] : q[0];
        float u = keep + __shfl_xor(send, 2);
        u += __shfl_xor(u, 4);
        u += __shfl_xor(u, 8);
        u += __shfl_xor(u, 16);
        u += __shfl_xor(u, 32);
        // each lane in a 4-lane group holds the full sum of a distinct row
        float dist = sqrtf(u);
        dist = fminf(fmaxf(dist, 1e-12f), 1e12f);
        // sum the 4 distinct rows within each 4-lane group
        dist += __shfl_xor(dist, 1);
        dist += __shfl_xor(dist, 2);
        p[0] = dist;   // every lane: sum of this wave's 4 row-distances
    }

    __shared__ float s[WAVES_PER_BLOCK];
    __shared__ int isLast;
    if (lane == 0) s[wave] = p[0];
    __syncthreads();

    if (threadIdx.x == 0) {
        float blk = 0.0f;
        #pragma unroll
        for (int i = 0; i < WAVES_PER_BLOCK; ++i) blk += s[i];
        ws[WS_PART + blockIdx.x] = blk;
        __threadfence();                                   // release partials + atomics
        unsigned old = atomicAdd((unsigned*)&ws[WS_DONE], 1u);
        isLast = (old == BLOCKS - 1);
    }
    __syncthreads();
    if (!isLast) return;

    // ---- final reduction: only the last-done block runs this ----
    __threadfence();                                       // acquire
    const int t = threadIdx.x;

#define WSLD(i) __hip_atomic_load(&ws[(i)], __ATOMIC_RELAXED, __HIP_MEMORY_SCOPE_AGENT)

    const float cnt0 = fmaxf(WSLD(WS_CNT0), 1.0f);
    const float cnt1 = fmaxf(WSLD(WS_CNT1), 1.0f);

    // inter: 512 dims over 512 threads (1 each)
    float a = (center[(size_t)(NUM_CLS - 2) * FEAT + t] + WSLD(WS_SUM0 + t)) / cnt0;
    float b = (center[(size_t)(NUM_CLS - 1) * FEAT + t] + WSLD(WS_SUM1 + t)) / cnt1;
    float df = a - b;
    float p_inter = df * df;

    // intra: 1024 block partials over 512 threads (2 each)
    float p_intra = WSLD(WS_PART + t) + WSLD(WS_PART + t + 512);

    #pragma unroll
    for (int off = 32; off; off >>= 1) {
        p_inter += __shfl_xor(p_inter, off);
        p_intra += __shfl_xor(p_intra, off);
    }

    __shared__ float si[WAVES_PER_BLOCK], sa[WAVES_PER_BLOCK];
    if ((t & 63) == 0) { si[t >> 6] = p_inter; sa[t >> 6] = p_intra; }
    __syncthreads();

    if (t == 0) {
        float s_inter = 0.0f, s_intra = 0.0f;
        #pragma unroll
        for (int i = 0; i < WAVES_PER_BLOCK; ++i) { s_inter += si[i]; s_intra += sa[i]; }
        float d_last = sqrtf(s_inter);
        out[0] = s_intra * (1.0f / (float)B_ROWS);
        out[1] = (2.0f / d_last) * (1.0f / ((float)NUM_CLS * (float)(NUM_CLS - 1)));
    }
}

extern "C" void kernel_launch(void* const* d_in, const int* in_sizes, int n_in,
                              void* d_out, int out_size, void* d_ws, size_t ws_size,
                              hipStream_t stream) {
    const float* features = (const float*)d_in[0];
    const int*   labels   = (const int*)d_in[1];
    const float* center   = (const float*)d_in[2];
    float* out = (float*)d_out;
    float* ws  = (float*)d_ws;

    (void)hipMemsetAsync(ws, 0, WS_ZERO_FLOATS * sizeof(float), stream);

    loss_fused<<<BLOCKS, THREADS, 0, stream>>>(features, labels, center, ws, out);
}

// Round 6
// 25.575 us; speedup vs baseline: 2.8770x; 2.3429x over previous
//
#include <hip/hip_runtime.h>

#define B_ROWS   32768
#define NUM_CLS  1000
#define FEAT     512

#define BLOCKS          2048
#define THREADS         256
#define WAVES_PER_BLOCK 4
#define ROWS_PER_WAVE   4      // 2048 * 4 * 4 = 32768

typedef float f32x4 __attribute__((ext_vector_type(4)));

// ws layout (floats):
//   [1]              count of class C-2
//   [2]              count of class C-1
//   [64 .. 576)      feature sums for class C-2
//   [576 .. 1088)    feature sums for class C-1
//   [1088 .. 3136)   per-block intra partials (plain stores, read next dispatch)
#define WS_CNT0   1
#define WS_CNT1   2
#define WS_SUM0   64
#define WS_SUM1   (64 + 512)
#define WS_PART   (64 + 1024)
#define WS_ZERO_FLOATS (64 + 1024)   // counts + class sums only

__global__ __launch_bounds__(THREADS) void loss_pass1(
    const float* __restrict__ features,
    const int*   __restrict__ labels,
    const float* __restrict__ center,
    float*       __restrict__ ws)
{
    const int wave = threadIdx.x >> 6;
    const int lane = threadIdx.x & 63;
    const int wid  = blockIdx.x * WAVES_PER_BLOCK + wave;
    const int base_row = wid * ROWS_PER_WAVE;

    // lanes 0..3 hold this wave's 4 labels (replicated in upper lanes)
    const int mylab = labels[base_row + (lane & 3)];

    float p[ROWS_PER_WAVE];

    #pragma unroll
    for (int r = 0; r < ROWS_PER_WAVE; ++r) {
        const int row = base_row + r;
        const int lab = __shfl(mylab, r);

        const f32x4* frow = (const f32x4*)(features + (size_t)row * FEAT);
        const f32x4* crow = (const f32x4*)(center   + (size_t)lab * FEAT);

        f32x4 f0 = frow[lane];
        f32x4 f1 = frow[lane + 64];
        f32x4 c0 = crow[lane];
        f32x4 c1 = crow[lane + 64];

        f32x4 d0 = f0 - c0;
        f32x4 d1 = f1 - c1;

        p[r] = d0.x*d0.x + d0.y*d0.y + d0.z*d0.z + d0.w*d0.w
             + d1.x*d1.x + d1.y*d1.y + d1.z*d1.z + d1.w*d1.w;

        // Inter-loss bookkeeping: classes C-2/C-1 only (~65 of 32768 rows)
        if (lab >= NUM_CLS - 2) {
            float* sums = ws + (lab == NUM_CLS - 2 ? WS_SUM0 : WS_SUM1);
            const int base = lane * 4;
            atomicAdd(&sums[base + 0],   f0.x);
            atomicAdd(&sums[base + 1],   f0.y);
            atomicAdd(&sums[base + 2],   f0.z);
            atomicAdd(&sums[base + 3],   f0.w);
            atomicAdd(&sums[base + 256], f1.x);
            atomicAdd(&sums[base + 257], f1.y);
            atomicAdd(&sums[base + 258], f1.z);
            atomicAdd(&sums[base + 259], f1.w);
            if (lane == 0)
                atomicAdd(&ws[lab == NUM_CLS - 2 ? WS_CNT0 : WS_CNT1], 1.0f);
        }
    }

    // ---- multi-value reduction: 4 row-sums across 64 lanes in 9 shuffles ----
    const bool b0 = lane & 1, b1 = lane & 2;

    float q[2];
    #pragma unroll
    for (int i = 0; i < 2; ++i) {
        float send = b0 ? p[i]     : p[2 + i];
        float keep = b0 ? p[2 + i] : p[i];
        q[i] = keep + __shfl_xor(send, 1);
    }
    {
        float send = b1 ? q[0] : q[1];
        float keep = b1 ? q[1] : q[0];
        float u = keep + __shfl_xor(send, 2);
        u += __shfl_xor(u, 4);
        u += __shfl_xor(u, 8);
        u += __shfl_xor(u, 16);
        u += __shfl_xor(u, 32);
        // each lane in a 4-lane group holds the full sum of a distinct row
        float dist = sqrtf(u);
        dist = fminf(fmaxf(dist, 1e-12f), 1e12f);
        dist += __shfl_xor(dist, 1);
        dist += __shfl_xor(dist, 2);
        p[0] = dist;   // every lane: sum of this wave's 4 row-distances
    }

    __shared__ float s[WAVES_PER_BLOCK];
    if (lane == 0) s[wave] = p[0];
    __syncthreads();
    if (threadIdx.x == 0)
        ws[WS_PART + blockIdx.x] = s[0] + s[1] + s[2] + s[3];  // unique slot, no atomic, no fence
}

__global__ __launch_bounds__(256) void loss_pass2(
    const float* __restrict__ center,
    const float* __restrict__ ws,
    float*       __restrict__ out)
{
    const int t = threadIdx.x;
    const float cnt0 = fmaxf(ws[WS_CNT0], 1.0f);
    const float cnt1 = fmaxf(ws[WS_CNT1], 1.0f);

    // inter: 512 dims over 256 threads (2 each)
    float p_inter = 0.0f;
    #pragma unroll
    for (int k = 0; k < 2; ++k) {
        const int d = t * 2 + k;
        float a = (center[(size_t)(NUM_CLS - 2) * FEAT + d] + ws[WS_SUM0 + d]) / cnt0;
        float b = (center[(size_t)(NUM_CLS - 1) * FEAT + d] + ws[WS_SUM1 + d]) / cnt1;
        float df = a - b;
        p_inter += df * df;
    }

    // intra: 2048 block partials over 256 threads (8 each)
    float p_intra = 0.0f;
    #pragma unroll
    for (int k = 0; k < 8; ++k)
        p_intra += ws[WS_PART + t + k * 256];

    #pragma unroll
    for (int off = 32; off; off >>= 1) {
        p_inter += __shfl_xor(p_inter, off);
        p_intra += __shfl_xor(p_intra, off);
    }

    __shared__ float si[4], sa[4];
    if ((t & 63) == 0) { si[t >> 6] = p_inter; sa[t >> 6] = p_intra; }
    __syncthreads();

    if (t == 0) {
        float d_last = sqrtf(si[0] + si[1] + si[2] + si[3]);
        out[0] = (sa[0] + sa[1] + sa[2] + sa[3]) * (1.0f / (float)B_ROWS);
        out[1] = (2.0f / d_last) * (1.0f / ((float)NUM_CLS * (float)(NUM_CLS - 1)));
    }
}

extern "C" void kernel_launch(void* const* d_in, const int* in_sizes, int n_in,
                              void* d_out, int out_size, void* d_ws, size_t ws_size,
                              hipStream_t stream) {
    const float* features = (const float*)d_in[0];
    const int*   labels   = (const int*)d_in[1];
    const float* center   = (const float*)d_in[2];
    float* out = (float*)d_out;
    float* ws  = (float*)d_ws;

    (void)hipMemsetAsync(ws, 0, WS_ZERO_FLOATS * sizeof(float), stream);

    loss_pass1<<<BLOCKS, THREADS, 0, stream>>>(features, labels, center, ws);
    loss_pass2<<<1, 256, 0, stream>>>(center, ws, out);
}